// Round 11
// baseline (249.683 us; speedup 1.0000x reference)
//
#include <hip/hip_runtime.h>
#include <hip/hip_bf16.h>
#include <cmath>

// Problem constants (HSTU layer): B=2, S=2048, D=1024, H=16, HD=64
#define BB 2
#define SS 2048
#define DD 1024
#define HH 16
#define EPS 1e-5f
#define LOG2E 1.44269504088896f
#define QSCALE (0.125f * LOG2E)   // HD^-0.5 * log2(e), folded into q

typedef __attribute__((ext_vector_type(8))) short short8;   // 8 bf16 (4 VGPRs)
typedef __attribute__((ext_vector_type(4))) float f32x4;    // 4 fp32 acc

__device__ inline unsigned short f2bf(float f) {
  union { float f; unsigned int u; } v; v.f = f;
  unsigned int u = v.u;
  unsigned int r = (u + 0x7FFFu + ((u >> 16) & 1u)) >> 16;  // RNE
  return (unsigned short)r;
}
__device__ inline float bf2f(unsigned short h) {
  union { unsigned int u; float f; } v; v.u = ((unsigned int)h) << 16;
  return v.f;
}
// fast pack: round-half-up (differs from RNE only at exact ties)
__device__ inline unsigned short f2bf_fast(float f) {
  union { float f; unsigned int u; } v; v.f = f;
  return (unsigned short)((v.u + 0x8000u) >> 16);
}

// ---------------------------------------------------------------------------
// Kernel 1: LayerNorm over D=1024, bf16 output. One block (256 thr) per row.
// ---------------------------------------------------------------------------
__global__ __launch_bounds__(256) void ln_kernel(
    const float* __restrict__ x, const float* __restrict__ gamma,
    const float* __restrict__ beta, unsigned short* __restrict__ xn) {
  int row = blockIdx.x;
  int t = threadIdx.x;
  const float* xr = x + (size_t)row * DD;
  float4 v = *(const float4*)(xr + t * 4);
  float s = v.x + v.y + v.z + v.w;
  float sq = v.x * v.x + v.y * v.y + v.z * v.z + v.w * v.w;
  for (int off = 32; off > 0; off >>= 1) {
    s += __shfl_down(s, off, 64);
    sq += __shfl_down(sq, off, 64);
  }
  __shared__ float ls[4], lq[4];
  int wave = t >> 6, lane = t & 63;
  if (lane == 0) { ls[wave] = s; lq[wave] = sq; }
  __syncthreads();
  float tot = ls[0] + ls[1] + ls[2] + ls[3];
  float totq = lq[0] + lq[1] + lq[2] + lq[3];
  float mu = tot * (1.0f / DD);
  float var = totq * (1.0f / DD) - mu * mu;
  float rstd = rsqrtf(var + EPS);
  float4 g = *(const float4*)(gamma + t * 4);
  float4 bt = *(const float4*)(beta + t * 4);
  ushort4 o;
  o.x = f2bf((v.x - mu) * rstd * g.x + bt.x);
  o.y = f2bf((v.y - mu) * rstd * g.y + bt.y);
  o.z = f2bf((v.z - mu) * rstd * g.z + bt.z);
  o.w = f2bf((v.w - mu) * rstd * g.w + bt.w);
  *(ushort4*)(xn + (size_t)row * DD + t * 4) = o;
}

// ---------------------------------------------------------------------------
// Kernel 2: merged transpose+cast: fp32 W[1024][N] -> bf16 Wt[N][1024]
// ---------------------------------------------------------------------------
__global__ __launch_bounds__(256) void wtrans_all(
    const float* __restrict__ wq, const float* __restrict__ wg,
    const float* __restrict__ wo, unsigned short* __restrict__ wcatT,
    unsigned short* __restrict__ woutT) {
  __shared__ unsigned short tile[32][33];
  int bx = blockIdx.x;  // 0..159
  const float* W;
  unsigned short* Wt;
  int N, colbase;
  if (bx < 96)       { W = wq; Wt = wcatT; N = 3072; colbase = bx * 32; }
  else if (bx < 128) { W = wg; Wt = wcatT + (size_t)3072 * 1024; N = 1024; colbase = (bx - 96) * 32; }
  else               { W = wo; Wt = woutT; N = 1024; colbase = (bx - 128) * 32; }
  int by = blockIdx.y * 32;  // K rows
  int tx = threadIdx.x & 31, ty = threadIdx.x >> 5;
#pragma unroll
  for (int i = 0; i < 32; i += 8)
    tile[ty + i][tx] = f2bf(W[(size_t)(by + ty + i) * N + colbase + tx]);
  __syncthreads();
#pragma unroll
  for (int i = 0; i < 32; i += 8)
    Wt[(size_t)(colbase + ty + i) * 1024 + by + tx] = tile[tx][ty + i];
}

// ---------------------------------------------------------------------------
// Kernel 3: fused QKV+gate bf16 MFMA GEMM. A[4096,1024] @ Wcat[4096,1024]^T.
// 128x128 tile, BK=32, 4 waves; register-prefetch. Sections (block-uniform):
//   [0,1024)    q    -> qkb[token][col], scaled by QSCALE (after bias)
//   [1024,2048) k    -> qkb[token][col]
//   [2048,3072) v    -> vT[(b*16+h)*64+d][s], via LDS transpose (coalesced)
//   [3072,4096) gate -> SiLU -> ub[token][col-3072]
// ---------------------------------------------------------------------------
__global__ __launch_bounds__(256) void gemm_qkvg(
    const unsigned short* __restrict__ A, const unsigned short* __restrict__ Bt,
    const float* __restrict__ bqkv, const float* __restrict__ bgate,
    unsigned short* __restrict__ qkb, unsigned short* __restrict__ vTb,
    unsigned short* __restrict__ ub) {
  __shared__ unsigned short SH[128 * 64];  // As | Bs; reused for v transpose
  unsigned short* As = SH;                 // 128*32
  unsigned short* Bs = SH + 128 * 32;      // 128*32
  const int K = 1024;
  int tid = threadIdx.x;
  int wave = tid >> 6, lane = tid & 63;
  int quad = lane >> 4, m16 = lane & 15;
  int wm = wave >> 1, wn = wave & 1;
  int m0 = blockIdx.y * 128, n0 = blockIdx.x * 128;

  int lrow = tid >> 2;
  int lcol = (tid & 3) * 8;
  const unsigned short* Ar0 = A + (size_t)(m0 + lrow) * K + lcol;
  const unsigned short* Ar1 = A + (size_t)(m0 + lrow + 64) * K + lcol;
  const unsigned short* Br0 = Bt + (size_t)(n0 + lrow) * K + lcol;
  const unsigned short* Br1 = Bt + (size_t)(n0 + lrow + 64) * K + lcol;

  f32x4 acc[4][4];
#pragma unroll
  for (int i = 0; i < 4; ++i)
#pragma unroll
    for (int j = 0; j < 4; ++j) acc[i][j] = (f32x4){0.f, 0.f, 0.f, 0.f};

  uint4 a0 = *(const uint4*)Ar0;
  uint4 a1 = *(const uint4*)Ar1;
  uint4 b0 = *(const uint4*)Br0;
  uint4 b1 = *(const uint4*)Br1;

  for (int k0 = 0; k0 < K; k0 += 32) {
    __syncthreads();
    *(uint4*)&As[lrow * 32 + lcol] = a0;
    *(uint4*)&As[(lrow + 64) * 32 + lcol] = a1;
    *(uint4*)&Bs[lrow * 32 + lcol] = b0;
    *(uint4*)&Bs[(lrow + 64) * 32 + lcol] = b1;
    __syncthreads();
    if (k0 + 32 < K) {  // prefetch next chunk; latency overlaps MFMA below
      a0 = *(const uint4*)(Ar0 + k0 + 32);
      a1 = *(const uint4*)(Ar1 + k0 + 32);
      b0 = *(const uint4*)(Br0 + k0 + 32);
      b1 = *(const uint4*)(Br1 + k0 + 32);
    }
    short8 af[4], bfr[4];
#pragma unroll
    for (int mi = 0; mi < 4; ++mi)
      af[mi] = *(const short8*)&As[(wm * 64 + mi * 16 + m16) * 32 + quad * 8];
#pragma unroll
    for (int ni = 0; ni < 4; ++ni)
      bfr[ni] = *(const short8*)&Bs[(wn * 64 + ni * 16 + m16) * 32 + quad * 8];
#pragma unroll
    for (int mi = 0; mi < 4; ++mi)
#pragma unroll
      for (int ni = 0; ni < 4; ++ni)
        acc[mi][ni] = __builtin_amdgcn_mfma_f32_16x16x32_bf16(
            af[mi], bfr[ni], acc[mi][ni], 0, 0, 0);
  }

  int sec = n0 >> 10;  // block-uniform: 0=q 1=k 2=v 3=gate
  if (sec == 2) {
    // ---- v section: LDS transpose -> coalesced vT[(b*16+h)*64+d][s] ----
    int bat = m0 >> 11;
    int s_base = m0 & 2047;     // 128-tile never crosses batch boundary
    int dgbase = n0 - 2048;     // 128-aligned v column base
#pragma unroll
    for (int p = 0; p < 2; ++p) {
      __syncthreads();  // SH free (MFMA reads / prev-pass reads done)
      if (wn == p) {
#pragma unroll
        for (int ni = 0; ni < 4; ++ni) {
          int dl = ni * 16 + m16;                 // 0..63
          float bb = bqkv[2048 + dgbase + p * 64 + dl];
#pragma unroll
          for (int mi = 0; mi < 4; ++mi)
#pragma unroll
            for (int r = 0; r < 4; ++r) {
              int sl = wm * 64 + mi * 16 + quad * 4 + r;   // 0..127
              int sls = sl ^ ((dl & 7) << 4);              // bank swizzle
              SH[dl * 128 + sls] = f2bf(acc[mi][ni][r] + bb);
            }
        }
      }
      __syncthreads();
      int dl = tid >> 2;                    // 0..63
      int dg = dgbase + p * 64 + dl;        // global v col 0..1023
      unsigned short* dst =
          vTb + ((size_t)(bat * 16 + (dg >> 6)) * 64 + (dg & 63)) * 2048 + s_base;
#pragma unroll
      for (int i = 0; i < 4; ++i) {
        int s0 = (tid & 3) * 8 + i * 32;
        int s0s = s0 ^ ((dl & 7) << 4);
        *(uint4*)(dst + s0) = *(const uint4*)&SH[dl * 128 + s0s];
      }
    }
  } else {
    int nwin = n0 + wn * 64;
    if (sec <= 1) {
      float qs = (sec == 0) ? QSCALE : 1.0f;
#pragma unroll
      for (int ni = 0; ni < 4; ++ni) {
        int col = nwin + ni * 16 + m16;
        float bb = bqkv[col];
#pragma unroll
        for (int mi = 0; mi < 4; ++mi)
#pragma unroll
          for (int r = 0; r < 4; ++r) {
            int row = m0 + wm * 64 + mi * 16 + quad * 4 + r;
            qkb[(size_t)row * 2048 + col] = f2bf((acc[mi][ni][r] + bb) * qs);
          }
      }
    } else {
#pragma unroll
      for (int ni = 0; ni < 4; ++ni) {
        int col = nwin + ni * 16 + m16;
        int g = col - 3072;
        float bb = bgate[g];
#pragma unroll
        for (int mi = 0; mi < 4; ++mi)
#pragma unroll
          for (int r = 0; r < 4; ++r) {
            int row = m0 + wm * 64 + mi * 16 + quad * 4 + r;
            float v = acc[mi][ni][r] + bb;
            v = v * __builtin_amdgcn_rcpf(1.0f + exp2f(-v * LOG2E));  // SiLU
            ub[(size_t)row * 1024 + g] = f2bf(v);
          }
      }
    }
  }
}

// ---------------------------------------------------------------------------
// Kernel 4: output GEMM: prod[4096,1024] @ wout[1024,1024]^T + b + x -> f32
// ---------------------------------------------------------------------------
__global__ __launch_bounds__(256) void gemm_out(
    const unsigned short* __restrict__ A, const unsigned short* __restrict__ Bt,
    const float* __restrict__ bias, const float* __restrict__ resid,
    float* __restrict__ C) {
  __shared__ unsigned short As[128 * 32];
  __shared__ unsigned short Bs[128 * 32];
  const int K = 1024, N = 1024;
  int tid = threadIdx.x;
  int wave = tid >> 6, lane = tid & 63;
  int quad = lane >> 4, m16 = lane & 15;
  int wm = wave >> 1, wn = wave & 1;
  int m0 = blockIdx.y * 128, n0 = blockIdx.x * 128;
  int lrow = tid >> 2;
  int lcol = (tid & 3) * 8;
  const unsigned short* Ar0 = A + (size_t)(m0 + lrow) * K + lcol;
  const unsigned short* Ar1 = A + (size_t)(m0 + lrow + 64) * K + lcol;
  const unsigned short* Br0 = Bt + (size_t)(n0 + lrow) * K + lcol;
  const unsigned short* Br1 = Bt + (size_t)(n0 + lrow + 64) * K + lcol;

  f32x4 acc[4][4];
#pragma unroll
  for (int i = 0; i < 4; ++i)
#pragma unroll
    for (int j = 0; j < 4; ++j) acc[i][j] = (f32x4){0.f, 0.f, 0.f, 0.f};

  uint4 a0 = *(const uint4*)Ar0;
  uint4 a1 = *(const uint4*)Ar1;
  uint4 b0 = *(const uint4*)Br0;
  uint4 b1 = *(const uint4*)Br1;

  for (int k0 = 0; k0 < K; k0 += 32) {
    __syncthreads();
    *(uint4*)&As[lrow * 32 + lcol] = a0;
    *(uint4*)&As[(lrow + 64) * 32 + lcol] = a1;
    *(uint4*)&Bs[lrow * 32 + lcol] = b0;
    *(uint4*)&Bs[(lrow + 64) * 32 + lcol] = b1;
    __syncthreads();
    if (k0 + 32 < K) {
      a0 = *(const uint4*)(Ar0 + k0 + 32);
      a1 = *(const uint4*)(Ar1 + k0 + 32);
      b0 = *(const uint4*)(Br0 + k0 + 32);
      b1 = *(const uint4*)(Br1 + k0 + 32);
    }
    short8 af[4], bfr[4];
#pragma unroll
    for (int mi = 0; mi < 4; ++mi)
      af[mi] = *(const short8*)&As[(wm * 64 + mi * 16 + m16) * 32 + quad * 8];
#pragma unroll
    for (int ni = 0; ni < 4; ++ni)
      bfr[ni] = *(const short8*)&Bs[(wn * 64 + ni * 16 + m16) * 32 + quad * 8];
#pragma unroll
    for (int mi = 0; mi < 4; ++mi)
#pragma unroll
      for (int ni = 0; ni < 4; ++ni)
        acc[mi][ni] = __builtin_amdgcn_mfma_f32_16x16x32_bf16(
            af[mi], bfr[ni], acc[mi][ni], 0, 0, 0);
  }
#pragma unroll
  for (int ni = 0; ni < 4; ++ni) {
    int col = n0 + wn * 64 + ni * 16 + m16;
    float bb = bias[col];
#pragma unroll
    for (int mi = 0; mi < 4; ++mi)
#pragma unroll
      for (int r = 0; r < 4; ++r) {
        int row = m0 + wm * 64 + mi * 16 + quad * 4 + r;
        C[(size_t)row * N + col] =
            acc[mi][ni][r] + bb + resid[(size_t)row * N + col];
      }
  }
}

// ---------------------------------------------------------------------------
// Kernel 5: MFMA sigmoid attention, causal, paired q-tiles, SPLIT-K.
// Grid (16, 32, 2): q-tile pair (qtA=bx, qtB=31-bx), bh, sk = k-parity.
// Block sk processes k-tiles kt ≡ sk (mod 2); each block ~16.5 tile-computes
// -> 1024 blocks = 16 waves/CU (2x occupancy vs round 10). Partial ctx
// written bf16 to ctxP[sk]; combined with *u in combine_kernel.
// Q in registers; K/V register-prefetch; Ps XOR-swizzled.
// ---------------------------------------------------------------------------
__global__ __launch_bounds__(256) void attn_mfma(
    const unsigned short* __restrict__ qk, const unsigned short* __restrict__ vT,
    const float* __restrict__ rpb,
    unsigned short* __restrict__ ctx0, unsigned short* __restrict__ ctx1) {
  __shared__ unsigned short Ks[64 * 72];
  __shared__ unsigned short Vs[64 * 72];   // Vt[d][key]
  __shared__ unsigned short Ps[64 * 72];   // wave-private rows, col-swizzled

  int qtA = blockIdx.x;         // 0..15
  int qtB = 31 - qtA;           // 16..31
  int q0A = qtA * 64, q0B = qtB * 64;
  int bh = blockIdx.y;
  int sk = blockIdx.z;          // k-parity 0/1
  int b = bh >> 4, h = bh & 15;
  int t = threadIdx.x;
  int wave = t >> 6, lane = t & 63;
  int quad = lane >> 4, m16 = lane & 15;

  const unsigned short* qbase = qk + (size_t)(b * SS) * 2048 + h * 64;
  const unsigned short* kbase = qbase + 1024;
  const unsigned short* vbase = vT + (size_t)bh * 64 * 2048;

  int row = t >> 3, blk8 = (t & 7) * 8;  // staging coords (32 rows x 64 cols)

  // Q fragments in registers (A-frag layout: lane m16 = q-row, cols quad*8+)
  short8 qfA[2], qfB[2];
#pragma unroll
  for (int s = 0; s < 2; ++s) {
    qfA[s] = *(const short8*)(qbase + (size_t)(q0A + wave * 16 + m16) * 2048 + s * 32 + quad * 8);
    qfB[s] = *(const short8*)(qbase + (size_t)(q0B + wave * 16 + m16) * 2048 + s * 32 + quad * 8);
  }

  f32x4 zero4 = {0.f, 0.f, 0.f, 0.f};
  f32x4 caccA[4], caccB[4];
#pragma unroll
  for (int nb = 0; nb < 4; ++nb) { caccA[nb] = zero4; caccB[nb] = zero4; }

  float hb2 = rpb[h] * LOG2E;
  float cexp = exp2f(-hb2);             // p = rcp(1 + cexp * 2^-s)
  int ktmax = qtB;
  int psw = quad << 3;                  // Ps write swizzle key
  int psr = ((m16 >> 2) & 3) << 3;      // Ps read un-swizzle key

  // preload kt=sk K/V into regs
  uint4 kv0, kv1, vv0, vv1;
  {
    int k00 = sk * 64;
    const unsigned short* kp = kbase + (size_t)(k00 + row) * 2048 + blk8;
    const unsigned short* vp = vbase + (size_t)row * 2048 + k00 + blk8;
    kv0 = *(const uint4*)kp;
    kv1 = *(const uint4*)(kp + (size_t)32 * 2048);
    vv0 = *(const uint4*)vp;
    vv1 = *(const uint4*)(vp + (size_t)32 * 2048);
  }

  for (int kt = sk; kt <= ktmax; kt += 2) {
    int k0 = kt * 64;
    __syncthreads();  // prev-iter readers of Ks/Vs done
    *(uint4*)&Ks[row * 72 + blk8] = kv0;
    *(uint4*)&Ks[(row + 32) * 72 + blk8] = kv1;
    *(uint4*)&Vs[row * 72 + blk8] = vv0;
    *(uint4*)&Vs[(row + 32) * 72 + blk8] = vv1;
    __syncthreads();
    if (kt + 2 <= ktmax) {  // prefetch next kt; latency overlaps compute
      int k0n = k0 + 128;
      const unsigned short* kp = kbase + (size_t)(k0n + row) * 2048 + blk8;
      const unsigned short* vp = vbase + (size_t)row * 2048 + k0n + blk8;
      kv0 = *(const uint4*)kp;
      kv1 = *(const uint4*)(kp + (size_t)32 * 2048);
      vv0 = *(const uint4*)vp;
      vv1 = *(const uint4*)(vp + (size_t)32 * 2048);
    }

#pragma unroll
    for (int tile = 0; tile < 2; ++tile) {
      if (tile == 1 && kt > qtA) break;
      const short8* qf = (tile == 0) ? qfB : qfA;
      int q0 = (tile == 0) ? q0B : q0A;
      bool diag = (tile == 0) ? (kt == qtB) : (kt == qtA);
      f32x4* cacc = (tile == 0) ? caccB : caccA;

      f32x4 sacc[4];
#pragma unroll
      for (int nb = 0; nb < 4; ++nb) sacc[nb] = zero4;
#pragma unroll
      for (int s = 0; s < 2; ++s) {
#pragma unroll
        for (int nb = 0; nb < 4; ++nb) {
          short8 bf = *(const short8*)&Ks[(nb * 16 + m16) * 72 + s * 32 + quad * 8];
          sacc[nb] = __builtin_amdgcn_mfma_f32_16x16x32_bf16(qf[s], bf, sacc[nb], 0, 0, 0);
        }
      }
#pragma unroll
      for (int nb = 0; nb < 4; ++nb) {
#pragma unroll
        for (int r = 0; r < 4; ++r) {
          float e = exp2f(-sacc[nb][r]);
          float p = __builtin_amdgcn_rcpf(fmaf(cexp, e, 1.0f));
          if (diag) {
            int key = k0 + nb * 16 + m16;
            int q = q0 + wave * 16 + quad * 4 + r;
            if (key > q) p = 0.f;
          }
          int colS = (nb * 16 + m16) ^ psw;  // conflict-free bank swizzle
          Ps[(wave * 16 + quad * 4 + r) * 72 + colS] = f2bf_fast(p);
        }
      }
      // no barrier: wave reads only its own Ps rows (in-wave LDS ordering)
#pragma unroll
      for (int s = 0; s < 2; ++s) {
        int pcol = (s * 32 + quad * 8) ^ psr;  // un-swizzle (8-contig)
        short8 a = *(const short8*)&Ps[(wave * 16 + m16) * 72 + pcol];
#pragma unroll
        for (int nb = 0; nb < 4; ++nb) {
          short8 bf = *(const short8*)&Vs[(nb * 16 + m16) * 72 + s * 32 + quad * 8];
          cacc[nb] = __builtin_amdgcn_mfma_f32_16x16x32_bf16(a, bf, cacc[nb], 0, 0, 0);
        }
      }
    }
  }

  // epilogue: write partial ctx (bf16) at [token][h*64+d]
  unsigned short* cp = (sk == 0) ? ctx0 : ctx1;
  unsigned short* cp_ = cp + (size_t)(b * SS) * 1024 + h * 64;
#pragma unroll
  for (int nb = 0; nb < 4; ++nb) {
    int d = nb * 16 + m16;
#pragma unroll
    for (int r = 0; r < 4; ++r) {
      int qA = q0A + wave * 16 + quad * 4 + r;
      int qB = q0B + wave * 16 + quad * 4 + r;
      cp_[(size_t)qA * 1024 + d] = f2bf(caccA[nb][r]);
      cp_[(size_t)qB * 1024 + d] = f2bf(caccB[nb][r]);
    }
  }
}

// ---------------------------------------------------------------------------
// Kernel 6: prod = bf16((ctx0 + ctx1) * u). 8 elems/thread, memory-bound.
// ---------------------------------------------------------------------------
__global__ __launch_bounds__(256) void combine_kernel(
    const unsigned short* __restrict__ c0, const unsigned short* __restrict__ c1,
    const unsigned short* __restrict__ u, unsigned short* __restrict__ prod) {
  size_t i = ((size_t)blockIdx.x * 256 + threadIdx.x) * 8;
  uint4 a = *(const uint4*)(c0 + i);
  uint4 b = *(const uint4*)(c1 + i);
  uint4 uu = *(const uint4*)(u + i);
  const unsigned short* ae = (const unsigned short*)&a;
  const unsigned short* be = (const unsigned short*)&b;
  const unsigned short* ue = (const unsigned short*)&uu;
  uint4 o;
  unsigned short* oe = (unsigned short*)&o;
#pragma unroll
  for (int j = 0; j < 8; ++j)
    oe[j] = f2bf((bf2f(ae[j]) + bf2f(be[j])) * bf2f(ue[j]));
  *(uint4*)(prod + i) = o;
}

// ---------------------------------------------------------------------------
extern "C" void kernel_launch(void* const* d_in, const int* in_sizes, int n_in,
                              void* d_out, int out_size, void* d_ws, size_t ws_size,
                              hipStream_t stream) {
  const float* x      = (const float*)d_in[0];
  // d_in[1] = attention_mask (causal tril) — computed analytically, not read
  const float* gamma  = (const float*)d_in[2];
  const float* beta   = (const float*)d_in[3];
  const float* w_qkv  = (const float*)d_in[4];
  const float* b_qkv  = (const float*)d_in[5];
  const float* w_gate = (const float*)d_in[6];
  const float* b_gate = (const float*)d_in[7];
  const float* w_out  = (const float*)d_in[8];
  const float* b_out  = (const float*)d_in[9];
  const float* rpb    = (const float*)d_in[10];
  float* out = (float*)d_out;

  unsigned short* xnb   = (unsigned short*)d_ws;  // 4096*1024
  unsigned short* qkb   = xnb + 4194304;          // 4096*2048 (q|k)
  unsigned short* vTb   = qkb + 8388608;          // 32*64*2048
  unsigned short* ub    = vTb + 4194304;          // 4096*1024
  unsigned short* prodb = ub + 4194304;           // 4096*1024
  unsigned short* ctx0b = prodb + 4194304;        // 4096*1024
  unsigned short* ctx1b = ctx0b + 4194304;        // 4096*1024
  unsigned short* wcatT = ctx1b + 4194304;        // 4096*1024 (qkv|gate rows)
  unsigned short* woutT = wcatT + 4194304;        // 1024*1024
  // total ~76 MB

  // 1. LayerNorm -> bf16
  ln_kernel<<<BB * SS, 256, 0, stream>>>(x, gamma, beta, xnb);
  // 2. Merged weight transposes fp32[K][N] -> bf16[N][K]
  wtrans_all<<<dim3(160, 32), 256, 0, stream>>>(w_qkv, w_gate, w_out, wcatT, woutT);
  // 3. Fused QKV+gate GEMM: N=4096 sections -> qkb, vTb (coalesced), ub
  gemm_qkvg<<<dim3(4096 / 128, 4096 / 128), 256, 0, stream>>>(
      xnb, wcatT, b_qkv, b_gate, qkb, vTb, ub);
  // 4. MFMA sigmoid attention, split-K (even/odd k-tiles) -> ctx0b, ctx1b
  attn_mfma<<<dim3(16, BB * HH, 2), 256, 0, stream>>>(qkb, vTb, rpb, ctx0b, ctx1b);
  // 5. prod = bf16((ctx0+ctx1) * u)
  combine_kernel<<<4194304 / (256 * 8), 256, 0, stream>>>(ctx0b, ctx1b, ub, prodb);
  // 6. Output projection: prod @ w_out + b_out + x -> f32 out
  gemm_out<<<dim3(1024 / 128, 4096 / 128), 256, 0, stream>>>(
      prodb, woutT, b_out, x, out);
}